// Round 1
// 142.789 us; speedup vs baseline: 1.0551x; 1.0551x over previous
//
#include <hip/hip_runtime.h>
#include <hip/hip_bf16.h>

#define HW_ 69696
#define W_ 264
#define H_ 264

typedef short bf16x8 __attribute__((ext_vector_type(8)));
typedef float f32x4 __attribute__((ext_vector_type(4)));

static __device__ __forceinline__ unsigned short f2b(float f) {
  __hip_bfloat16 h = __float2bfloat16(f);
  return *reinterpret_cast<unsigned short*>(&h);
}
static __device__ __forceinline__ float b2f(unsigned short u) {
  __hip_bfloat16 h;
  *reinterpret_cast<unsigned short*>(&h) = u;
  return __bfloat162float(h);
}
static __device__ __forceinline__ float lo_f(unsigned int u) {
  union { unsigned int i; float f; } c; c.i = u << 16; return c.f;
}
static __device__ __forceinline__ float hi_f(unsigned int u) {
  union { unsigned int i; float f; } c; c.i = u & 0xffff0000u; return c.f;
}

// ---------------- k_gemm v2: qkv = W(288x96) @ roll(x), B in registers, 3 oc in-block ----------------
__global__ __launch_bounds__(256, 4) void k_gemm(const float* __restrict__ x,
                                                 const float* __restrict__ w,
                                                 unsigned short* __restrict__ outb) {
  __shared__ __align__(16) char smem[19968];
  unsigned short* As = (unsigned short*)smem;   // [96][104]
  unsigned short* Cs = (unsigned short*)smem;   // [64][104] overlay (epilogue)

  const int tid = threadIdx.x;
  const int wid = tid >> 6, lane = tid & 63;
  const int quad = lane >> 4, lo = lane & 15;
  const int px0 = blockIdx.x * 64;
  const int px = px0 + wid * 16 + lo;

  const int y = px / W_, xx = px - y * W_;
  int y2 = y + 4; if (y2 >= H_) y2 -= H_;
  int x2 = xx + 4; if (x2 >= W_) x2 -= W_;
  const float* xb = x + y2 * W_ + x2;

  bf16x8 bf[3];
#pragma unroll
  for (int ks = 0; ks < 3; ++ks) {
    const float* xp = xb + (size_t)(ks * 32 + quad * 8) * HW_;
    float f[8];
#pragma unroll
    for (int i = 0; i < 8; ++i) f[i] = xp[(size_t)i * HW_];
    union { bf16x8 v; unsigned short s[8]; } u;
#pragma unroll
    for (int i = 0; i < 8; ++i) u.s[i] = f2b(f[i]);
    bf[ks] = u.v;
  }

  for (int oc = 0; oc < 3; ++oc) {
    __syncthreads();
    const float* wp = w + oc * 96 * 96;
    for (int l = tid; l < 96 * 24; l += 256) {
      int o = l / 24, c4 = (l - (l / 24) * 24) * 4;
      float4 v = *(const float4*)&wp[o * 96 + c4];
      unsigned int p0 = (unsigned int)f2b(v.x) | ((unsigned int)f2b(v.y) << 16);
      unsigned int p1 = (unsigned int)f2b(v.z) | ((unsigned int)f2b(v.w) << 16);
      *(uint2*)&As[o * 104 + c4] = make_uint2(p0, p1);
    }
    __syncthreads();

    f32x4 acc[6];
#pragma unroll
    for (int mt = 0; mt < 6; ++mt) acc[mt] = {0.f, 0.f, 0.f, 0.f};
#pragma unroll
    for (int ks = 0; ks < 3; ++ks) {
      const int kb = ks * 32 + quad * 8;
#pragma unroll
      for (int mt = 0; mt < 6; ++mt) {
        bf16x8 a = *(const bf16x8*)&As[(mt * 16 + lo) * 104 + kb];
        acc[mt] = __builtin_amdgcn_mfma_f32_16x16x32_bf16(a, bf[ks], acc[mt], 0, 0, 0);
      }
    }
    __syncthreads();

    const int pxl = wid * 16 + lo;
#pragma unroll
    for (int mt = 0; mt < 6; ++mt) {
      unsigned int p0 = (unsigned int)f2b(acc[mt][0]) | ((unsigned int)f2b(acc[mt][1]) << 16);
      unsigned int p1 = (unsigned int)f2b(acc[mt][2]) | ((unsigned int)f2b(acc[mt][3]) << 16);
      *(uint2*)&Cs[pxl * 104 + mt * 16 + quad * 4] = make_uint2(p0, p1);
    }
    __syncthreads();

    for (int i = tid; i < 64 * 12; i += 256) {
      int pxl2 = i & 63, j = i >> 6;
      *((uint4*)outb + (size_t)(oc * 12 + j) * HW_ + px0 + pxl2) =
          ((const uint4*)(Cs + pxl2 * 104))[j];
    }
  }
}

// ---------------- k_dwattn: fused 3x3 depthwise + windowed channel attention ----------------
// One block = one 8x8 window of one tile. dw computed from image-space 10x10 qkvb halo
// (dw precedes TLC tiling in the reference, so halos come straight from qkvb).
// LDS: outS [64px][296ch] bf16 (37.9K, Cs overlays in epilogue) + per-wave 10x10 stage
// (6.4K) + attnL (7.7K) + invn -> 52.4KB -> 3 blocks/CU.
__global__ __launch_bounds__(256, 3) void k_dwattn(const unsigned short* __restrict__ qkvb,
                                                   const float* __restrict__ dwv,
                                                   const float* __restrict__ temp,
                                                   unsigned short* __restrict__ tout) {
  __shared__ __align__(16) unsigned short outS[64 * 296];   // 37,888 B
  __shared__ __align__(16) uint4 stg[4][100];               //  6,400 B
  __shared__ __align__(16) unsigned short attnL[3 * 32 * 40];
  __shared__ float invn[3 * 32];

  const int tid = threadIdx.x;
  // XCD-chunked window swizzle: same-XCD blocks become spatially adjacent windows.
  const int wi = ((blockIdx.x & 7) << 3) | (blockIdx.x >> 3);
  const int t = blockIdx.y;
  const int i0 = (t / 5) * 50, j0 = (t % 5) * 50;
  const int wy = wi >> 3, wx = wi & 7;
  const int gy0 = i0 + wy * 8, gx0 = j0 + wx * 8;

  const int h = tid >> 6, lane = tid & 63;
  const int w_ = __builtin_amdgcn_readfirstlane(h);   // wave id, SGPR

  // ---------- dw phase: wave w handles planes u = 4k + w, k = 0..8 ----------
  {
    uint4* stgW = &stg[w_][0];
    const int r0 = lane >> 3, c0 = lane & 7;            // this lane's window px
    const int sy0 = lane / 10, sx0 = lane - sy0 * 10;   // staging slot A (idx = lane)
    const int ii1 = lane + 64;                          // staging slot B
    const int sy1 = ii1 / 10, sx1 = ii1 - sy1 * 10;
    const int gyA = gy0 - 1 + sy0, gxA = gx0 - 1 + sx0;
    const int gyB = gy0 - 1 + sy1, gxB = gx0 - 1 + sx1;
    const bool okA = (unsigned)gyA < (unsigned)H_ && (unsigned)gxA < (unsigned)W_;
    const bool okB = ii1 < 100 && (unsigned)gyB < (unsigned)H_ && (unsigned)gxB < (unsigned)W_;
    const size_t offA = (size_t)gyA * W_ + gxA;
    const size_t offB = (size_t)gyB * W_ + gxB;
    const uint4* qb4 = (const uint4*)qkvb;

    uint4 vA = okA ? qb4[(size_t)w_ * HW_ + offA] : make_uint4(0u, 0u, 0u, 0u);
    uint4 vB = okB ? qb4[(size_t)w_ * HW_ + offB] : make_uint4(0u, 0u, 0u, 0u);

    for (int k = 0; k < 9; ++k) {
      const int u = k * 4 + w_;
      stgW[lane] = vA;
      if (ii1 < 100) stgW[ii1] = vB;
      if (k < 8) {  // prefetch next plane's halo (overlaps with compute below)
        vA = okA ? qb4[(size_t)(u + 4) * HW_ + offA] : make_uint4(0u, 0u, 0u, 0u);
        vB = okB ? qb4[(size_t)(u + 4) * HW_ + offB] : make_uint4(0u, 0u, 0u, 0u);
      }
      // wave-synchronous LDS: drain ds_writes before reads (same wave only)
      asm volatile("s_waitcnt lgkmcnt(0)" ::: "memory");
      __builtin_amdgcn_sched_barrier(0);

      const float* wp = dwv + u * 72;   // u is wave-uniform -> s_loads
      float acc[8] = {0.f, 0.f, 0.f, 0.f, 0.f, 0.f, 0.f, 0.f};
#pragma unroll
      for (int dy = 0; dy < 3; ++dy)
#pragma unroll
        for (int dx = 0; dx < 3; ++dx) {
          uint4 v = stgW[(r0 + dy) * 10 + (c0 + dx)];
          float w0 = wp[0 * 9 + dy * 3 + dx], w1 = wp[1 * 9 + dy * 3 + dx];
          float w2 = wp[2 * 9 + dy * 3 + dx], w3 = wp[3 * 9 + dy * 3 + dx];
          float w4 = wp[4 * 9 + dy * 3 + dx], w5 = wp[5 * 9 + dy * 3 + dx];
          float w6 = wp[6 * 9 + dy * 3 + dx], w7 = wp[7 * 9 + dy * 3 + dx];
          acc[0] += w0 * lo_f(v.x); acc[1] += w1 * hi_f(v.x);
          acc[2] += w2 * lo_f(v.y); acc[3] += w3 * hi_f(v.y);
          acc[4] += w4 * lo_f(v.z); acc[5] += w5 * hi_f(v.z);
          acc[6] += w6 * lo_f(v.w); acc[7] += w7 * hi_f(v.w);
        }
      uint4 o;
      o.x = (unsigned int)f2b(acc[0]) | ((unsigned int)f2b(acc[1]) << 16);
      o.y = (unsigned int)f2b(acc[2]) | ((unsigned int)f2b(acc[3]) << 16);
      o.z = (unsigned int)f2b(acc[4]) | ((unsigned int)f2b(acc[5]) << 16);
      o.w = (unsigned int)f2b(acc[6]) | ((unsigned int)f2b(acc[7]) << 16);
      *(uint4*)&outS[lane * 296 + u * 8] = o;
    }
  }
  __syncthreads();

  // ---------- attention phase (R7 attn verbatim, source = outS [px][ch]) ----------
  const int quad = lane >> 4, lo = lane & 15;
  const int cb = h * 32;

  bf16x8 qf[2][2], kf[2][2];
  f32x4 S[2][2];
  float ivk[2];
  if (h < 3) {
#pragma unroll
    for (int mt = 0; mt < 2; ++mt)
#pragma unroll
      for (int kt = 0; kt < 2; ++kt) {
        const int rr = kt * 4 + quad;
        const int cq = cb + mt * 16 + lo;
        const int ck = 96 + cq;
        bf16x8 q8, k8;
#pragma unroll
        for (int j = 0; j < 8; ++j) {
          q8[j] = (short)outS[(rr * 8 + j) * 296 + cq];
          k8[j] = (short)outS[(rr * 8 + j) * 296 + ck];
        }
        qf[mt][kt] = q8;
        kf[mt][kt] = k8;
      }

#pragma unroll
    for (int mt = 0; mt < 2; ++mt)
#pragma unroll
      for (int nt = 0; nt < 2; ++nt) {
        S[mt][nt] = {0.f, 0.f, 0.f, 0.f};
#pragma unroll
        for (int kt = 0; kt < 2; ++kt)
          S[mt][nt] = __builtin_amdgcn_mfma_f32_16x16x32_bf16(qf[mt][kt], kf[nt][kt], S[mt][nt], 0, 0, 0);
      }

#pragma unroll
    for (int mt = 0; mt < 2; ++mt) {
      float sq = 0.f, sk = 0.f;
#pragma unroll
      for (int kt = 0; kt < 2; ++kt)
#pragma unroll
        for (int j = 0; j < 8; ++j) {
          float a = b2f((unsigned short)qf[mt][kt][j]);
          float b = b2f((unsigned short)kf[mt][kt][j]);
          sq += a * a;
          sk += b * b;
        }
      sq += __shfl_xor(sq, 16);
      sq += __shfl_xor(sq, 32);
      sk += __shfl_xor(sk, 16);
      sk += __shfl_xor(sk, 32);
      if (quad == 0) invn[h * 32 + mt * 16 + lo] = 1.f / fmaxf(sqrtf(sq), 1e-12f);
      ivk[mt] = 1.f / fmaxf(sqrtf(sk), 1e-12f);
    }
  }
  __syncthreads();

  if (h < 3) {
    const float ts = temp[h];
#pragma unroll
    for (int mt = 0; mt < 2; ++mt)
#pragma unroll
      for (int nt = 0; nt < 2; ++nt)
#pragma unroll
        for (int r = 0; r < 4; ++r) {
          int c = mt * 16 + quad * 4 + r;
          float v = S[mt][nt][r] * invn[h * 32 + c] * ivk[nt] * ts;
          attnL[(h * 32 + c) * 40 + nt * 16 + lo] = f2b(fmaxf(v, 0.f));
        }
  }
  __syncthreads();

  f32x4 O[2][4];
  if (h < 3) {
    bf16x8 af[2];
#pragma unroll
    for (int mt = 0; mt < 2; ++mt)
      af[mt] = *(const bf16x8*)&attnL[(h * 32 + mt * 16 + lo) * 40 + quad * 8];

    const int uv = 24 + h * 4 + quad;
#pragma unroll
    for (int nt = 0; nt < 4; ++nt) {
      const int px = nt * 16 + lo;
      uint4 vraw = *(const uint4*)&outS[px * 296 + uv * 8];
      bf16x8 vf = *reinterpret_cast<bf16x8*>(&vraw);
#pragma unroll
      for (int mt = 0; mt < 2; ++mt) {
        f32x4 z = {0.f, 0.f, 0.f, 0.f};
        O[mt][nt] = __builtin_amdgcn_mfma_f32_16x16x32_bf16(af[mt], vf, z, 0, 0, 0);
      }
    }
  }
  __syncthreads();   // outS (V) dead -> Cs overlay

  unsigned short* Cs = outS;  // [64 px][104] overlay
  if (h < 3) {
#pragma unroll
    for (int mt = 0; mt < 2; ++mt)
#pragma unroll
      for (int nt = 0; nt < 4; ++nt) {
        const int px = nt * 16 + lo;
        unsigned int p0 = (unsigned int)f2b(O[mt][nt][0]) | ((unsigned int)f2b(O[mt][nt][1]) << 16);
        unsigned int p1 = (unsigned int)f2b(O[mt][nt][2]) | ((unsigned int)f2b(O[mt][nt][3]) << 16);
        *(uint2*)&Cs[px * 104 + cb + mt * 16 + quad * 4] = make_uint2(p0, p1);
      }
  }
  __syncthreads();

  for (int idx = tid; idx < 64 * 12; idx += 256) {
    int rec = idx / 12, u = idx - (idx / 12) * 12;
    int r = rec >> 3, j = rec & 7;
    size_t g = (size_t)t * 4096 + (wy * 8 + r) * 64 + wx * 8 + j;
    ((uint4*)tout)[g * 12 + u] = ((const uint4*)(Cs + rec * 104))[u];
  }
}

// ---------------- k_avgproj v2: per-lane averaged B fragments, A-only LDS ----------------
__global__ __launch_bounds__(256, 4) void k_avgproj(const float* __restrict__ w,
                                                    const unsigned short* __restrict__ tout,
                                                    float* __restrict__ outf) {
  __shared__ __align__(16) unsigned short As[96 * 104];
  const int tid = threadIdx.x;
  const int wid = tid >> 6, lane = tid & 63;
  const int quad = lane >> 4, lo = lane & 15;
  const int px0 = blockIdx.x * 64;
  const int px = px0 + wid * 16 + lo;

  for (int l = tid; l < 96 * 24; l += 256) {
    int o = l / 24, c4 = (l - (l / 24) * 24) * 4;
    float4 v = *(const float4*)&w[o * 96 + c4];
    unsigned int p0 = (unsigned int)f2b(v.x) | ((unsigned int)f2b(v.y) << 16);
    unsigned int p1 = (unsigned int)f2b(v.z) | ((unsigned int)f2b(v.w) << 16);
    *(uint2*)&As[o * 104 + c4] = make_uint2(p0, p1);
  }

  const int y = px / W_, xx = px - y * W_;
  int loy = (y >= 64) ? (y - 14) / 50 : 0;
  int hiy = y / 50; if (hiy > 4) hiy = 4;
  int lox = (xx >= 64) ? (xx - 14) / 50 : 0;
  int hix = xx / 50; if (hix > 4) hix = 4;
  float a24[24];
#pragma unroll
  for (int i = 0; i < 24; ++i) a24[i] = 0.f;
  int cnt = 0;
  for (int ty = loy; ty <= hiy; ++ty)
    for (int tx = lox; tx <= hix; ++tx) {
      size_t rec = (size_t)(ty * 5 + tx) * 4096 + ((y - ty * 50) << 6) + (xx - tx * 50);
      const uint4* rp = (const uint4*)tout + rec * 12 + quad;
#pragma unroll
      for (int ks = 0; ks < 3; ++ks) {
        uint4 v = rp[ks * 4];
        a24[ks * 8 + 0] += lo_f(v.x); a24[ks * 8 + 1] += hi_f(v.x);
        a24[ks * 8 + 2] += lo_f(v.y); a24[ks * 8 + 3] += hi_f(v.y);
        a24[ks * 8 + 4] += lo_f(v.z); a24[ks * 8 + 5] += hi_f(v.z);
        a24[ks * 8 + 6] += lo_f(v.w); a24[ks * 8 + 7] += hi_f(v.w);
      }
      ++cnt;
    }
  const float inv = 1.f / (float)cnt;
  bf16x8 bf[3];
#pragma unroll
  for (int ks = 0; ks < 3; ++ks) {
    union { bf16x8 v; unsigned short s[8]; } u;
#pragma unroll
    for (int i = 0; i < 8; ++i) u.s[i] = f2b(a24[ks * 8 + i] * inv);
    bf[ks] = u.v;
  }
  __syncthreads();

  f32x4 acc[6];
#pragma unroll
  for (int mt = 0; mt < 6; ++mt) acc[mt] = {0.f, 0.f, 0.f, 0.f};
#pragma unroll
  for (int ks = 0; ks < 3; ++ks) {
    const int kb = ks * 32 + quad * 8;
#pragma unroll
    for (int mt = 0; mt < 6; ++mt) {
      bf16x8 a = *(const bf16x8*)&As[(mt * 16 + lo) * 104 + kb];
      acc[mt] = __builtin_amdgcn_mfma_f32_16x16x32_bf16(a, bf[ks], acc[mt], 0, 0, 0);
    }
  }

  {
    int y2 = y + 4; if (y2 >= H_) y2 -= H_;
    int x2 = xx + 4; if (x2 >= W_) x2 -= W_;
    int tp = y2 * W_ + x2;
#pragma unroll
    for (int mt = 0; mt < 6; ++mt) {
      int row = mt * 16 + quad * 4;
#pragma unroll
      for (int r = 0; r < 4; ++r)
        outf[(size_t)(row + r) * HW_ + tp] = acc[mt][r];
    }
  }
}

extern "C" void kernel_launch(void* const* d_in, const int* in_sizes, int n_in,
                              void* d_out, int out_size, void* d_ws, size_t ws_size,
                              hipStream_t stream) {
  (void)in_sizes; (void)n_in; (void)out_size; (void)ws_size;
  const float* x = (const float*)d_in[0];
  const float* temp = (const float*)d_in[1];
  const float* qkvw = (const float*)d_in[2];
  const float* dww = (const float*)d_in[3];
  const float* projw = (const float*)d_in[4];
  float* out = (float*)d_out;

  char* ws = (char*)d_ws;
  const size_t SZQ = (size_t)288 * HW_ * 2;  // 40,144,896 B
  // [0, SZQ):            qkvb planes (read by fused k_dwattn)
  // [SZQ, SZQ+19.7MB):   tout records (qkvd region is gone -- dw fused into attn)
  unsigned short* qkvb = (unsigned short*)ws;
  unsigned short* tout = (unsigned short*)(ws + SZQ);

  k_gemm<<<dim3(1089), 256, 0, stream>>>(x, qkvw, qkvb);
  k_dwattn<<<dim3(64, 25), 256, 0, stream>>>(qkvb, dww, temp, tout);
  k_avgproj<<<dim3(1089), 256, 0, stream>>>(projw, tout, out);
}

// Round 2
// 141.731 us; speedup vs baseline: 1.0629x; 1.0075x over previous
//
#include <hip/hip_runtime.h>
#include <hip/hip_bf16.h>

#define HW_ 69696
#define W_ 264
#define H_ 264

typedef short bf16x8 __attribute__((ext_vector_type(8)));
typedef float f32x4 __attribute__((ext_vector_type(4)));

static __device__ __forceinline__ unsigned short f2b(float f) {
  __hip_bfloat16 h = __float2bfloat16(f);
  return *reinterpret_cast<unsigned short*>(&h);
}
static __device__ __forceinline__ float b2f(unsigned short u) {
  __hip_bfloat16 h;
  *reinterpret_cast<unsigned short*>(&h) = u;
  return __bfloat162float(h);
}
static __device__ __forceinline__ float lo_f(unsigned int u) {
  union { unsigned int i; float f; } c; c.i = u << 16; return c.f;
}
static __device__ __forceinline__ float hi_f(unsigned int u) {
  union { unsigned int i; float f; } c; c.i = u & 0xffff0000u; return c.f;
}

// ---------------- k_gemm v2: qkv = W(288x96) @ roll(x), B in registers, 3 oc in-block ----------------
__global__ __launch_bounds__(256, 4) void k_gemm(const float* __restrict__ x,
                                                 const float* __restrict__ w,
                                                 unsigned short* __restrict__ outb) {
  __shared__ __align__(16) char smem[19968];
  unsigned short* As = (unsigned short*)smem;   // [96][104]
  unsigned short* Cs = (unsigned short*)smem;   // [64][104] overlay (epilogue)

  const int tid = threadIdx.x;
  const int wid = tid >> 6, lane = tid & 63;
  const int quad = lane >> 4, lo = lane & 15;
  const int px0 = blockIdx.x * 64;
  const int px = px0 + wid * 16 + lo;

  const int y = px / W_, xx = px - y * W_;
  int y2 = y + 4; if (y2 >= H_) y2 -= H_;
  int x2 = xx + 4; if (x2 >= W_) x2 -= W_;
  const float* xb = x + y2 * W_ + x2;

  bf16x8 bf[3];
#pragma unroll
  for (int ks = 0; ks < 3; ++ks) {
    const float* xp = xb + (size_t)(ks * 32 + quad * 8) * HW_;
    float f[8];
#pragma unroll
    for (int i = 0; i < 8; ++i) f[i] = xp[(size_t)i * HW_];
    union { bf16x8 v; unsigned short s[8]; } u;
#pragma unroll
    for (int i = 0; i < 8; ++i) u.s[i] = f2b(f[i]);
    bf[ks] = u.v;
  }

  for (int oc = 0; oc < 3; ++oc) {
    __syncthreads();
    const float* wp = w + oc * 96 * 96;
    for (int l = tid; l < 96 * 24; l += 256) {
      int o = l / 24, c4 = (l - (l / 24) * 24) * 4;
      float4 v = *(const float4*)&wp[o * 96 + c4];
      unsigned int p0 = (unsigned int)f2b(v.x) | ((unsigned int)f2b(v.y) << 16);
      unsigned int p1 = (unsigned int)f2b(v.z) | ((unsigned int)f2b(v.w) << 16);
      *(uint2*)&As[o * 104 + c4] = make_uint2(p0, p1);
    }
    __syncthreads();

    f32x4 acc[6];
#pragma unroll
    for (int mt = 0; mt < 6; ++mt) acc[mt] = {0.f, 0.f, 0.f, 0.f};
#pragma unroll
    for (int ks = 0; ks < 3; ++ks) {
      const int kb = ks * 32 + quad * 8;
#pragma unroll
      for (int mt = 0; mt < 6; ++mt) {
        bf16x8 a = *(const bf16x8*)&As[(mt * 16 + lo) * 104 + kb];
        acc[mt] = __builtin_amdgcn_mfma_f32_16x16x32_bf16(a, bf[ks], acc[mt], 0, 0, 0);
      }
    }
    __syncthreads();

    const int pxl = wid * 16 + lo;
#pragma unroll
    for (int mt = 0; mt < 6; ++mt) {
      unsigned int p0 = (unsigned int)f2b(acc[mt][0]) | ((unsigned int)f2b(acc[mt][1]) << 16);
      unsigned int p1 = (unsigned int)f2b(acc[mt][2]) | ((unsigned int)f2b(acc[mt][3]) << 16);
      *(uint2*)&Cs[pxl * 104 + mt * 16 + quad * 4] = make_uint2(p0, p1);
    }
    __syncthreads();

    for (int i = tid; i < 64 * 12; i += 256) {
      int pxl2 = i & 63, j = i >> 6;
      *((uint4*)outb + (size_t)(oc * 12 + j) * HW_ + px0 + pxl2) =
          ((const uint4*)(Cs + pxl2 * 104))[j];
    }
  }
}

// ---------------- k_dwattn: fused 3x3 depthwise + windowed channel attention ----------------
// One block = one 8x8 window of one tile. dw computed from image-space 10x10 qkvb halo.
// tout layout is PLANE-MAJOR per tile: [tile][12 planes][4096 px] uint4, so the
// k_avgproj gather is coalesced (consecutive px -> consecutive 16B records).
__global__ __launch_bounds__(256, 3) void k_dwattn(const unsigned short* __restrict__ qkvb,
                                                   const float* __restrict__ dwv,
                                                   const float* __restrict__ temp,
                                                   unsigned short* __restrict__ tout) {
  __shared__ __align__(16) unsigned short outS[64 * 296];   // 37,888 B
  __shared__ __align__(16) uint4 stg[4][100];               //  6,400 B
  __shared__ __align__(16) unsigned short attnL[3 * 32 * 40];
  __shared__ float invn[3 * 32];

  const int tid = threadIdx.x;
  // XCD-chunked window swizzle: same-XCD blocks become spatially adjacent windows.
  const int wi = ((blockIdx.x & 7) << 3) | (blockIdx.x >> 3);
  const int t = blockIdx.y;
  const int i0 = (t / 5) * 50, j0 = (t % 5) * 50;
  const int wy = wi >> 3, wx = wi & 7;
  const int gy0 = i0 + wy * 8, gx0 = j0 + wx * 8;

  const int h = tid >> 6, lane = tid & 63;
  const int w_ = __builtin_amdgcn_readfirstlane(h);   // wave id, SGPR

  // ---------- dw phase: wave w handles planes u = 4k + w, k = 0..8 ----------
  {
    uint4* stgW = &stg[w_][0];
    const int r0 = lane >> 3, c0 = lane & 7;
    const int sy0 = lane / 10, sx0 = lane - sy0 * 10;
    const int ii1 = lane + 64;
    const int sy1 = ii1 / 10, sx1 = ii1 - sy1 * 10;
    const int gyA = gy0 - 1 + sy0, gxA = gx0 - 1 + sx0;
    const int gyB = gy0 - 1 + sy1, gxB = gx0 - 1 + sx1;
    const bool okA = (unsigned)gyA < (unsigned)H_ && (unsigned)gxA < (unsigned)W_;
    const bool okB = ii1 < 100 && (unsigned)gyB < (unsigned)H_ && (unsigned)gxB < (unsigned)W_;
    const size_t offA = (size_t)gyA * W_ + gxA;
    const size_t offB = (size_t)gyB * W_ + gxB;
    const uint4* qb4 = (const uint4*)qkvb;

    uint4 vA = okA ? qb4[(size_t)w_ * HW_ + offA] : make_uint4(0u, 0u, 0u, 0u);
    uint4 vB = okB ? qb4[(size_t)w_ * HW_ + offB] : make_uint4(0u, 0u, 0u, 0u);

    for (int k = 0; k < 9; ++k) {
      const int u = k * 4 + w_;
      stgW[lane] = vA;
      if (ii1 < 100) stgW[ii1] = vB;
      if (k < 8) {
        vA = okA ? qb4[(size_t)(u + 4) * HW_ + offA] : make_uint4(0u, 0u, 0u, 0u);
        vB = okB ? qb4[(size_t)(u + 4) * HW_ + offB] : make_uint4(0u, 0u, 0u, 0u);
      }
      asm volatile("s_waitcnt lgkmcnt(0)" ::: "memory");
      __builtin_amdgcn_sched_barrier(0);

      const float* wp = dwv + u * 72;
      float acc[8] = {0.f, 0.f, 0.f, 0.f, 0.f, 0.f, 0.f, 0.f};
#pragma unroll
      for (int dy = 0; dy < 3; ++dy)
#pragma unroll
        for (int dx = 0; dx < 3; ++dx) {
          uint4 v = stgW[(r0 + dy) * 10 + (c0 + dx)];
          float w0 = wp[0 * 9 + dy * 3 + dx], w1 = wp[1 * 9 + dy * 3 + dx];
          float w2 = wp[2 * 9 + dy * 3 + dx], w3 = wp[3 * 9 + dy * 3 + dx];
          float w4 = wp[4 * 9 + dy * 3 + dx], w5 = wp[5 * 9 + dy * 3 + dx];
          float w6 = wp[6 * 9 + dy * 3 + dx], w7 = wp[7 * 9 + dy * 3 + dx];
          acc[0] += w0 * lo_f(v.x); acc[1] += w1 * hi_f(v.x);
          acc[2] += w2 * lo_f(v.y); acc[3] += w3 * hi_f(v.y);
          acc[4] += w4 * lo_f(v.z); acc[5] += w5 * hi_f(v.z);
          acc[6] += w6 * lo_f(v.w); acc[7] += w7 * hi_f(v.w);
        }
      uint4 o;
      o.x = (unsigned int)f2b(acc[0]) | ((unsigned int)f2b(acc[1]) << 16);
      o.y = (unsigned int)f2b(acc[2]) | ((unsigned int)f2b(acc[3]) << 16);
      o.z = (unsigned int)f2b(acc[4]) | ((unsigned int)f2b(acc[5]) << 16);
      o.w = (unsigned int)f2b(acc[6]) | ((unsigned int)f2b(acc[7]) << 16);
      *(uint4*)&outS[lane * 296 + u * 8] = o;
    }
  }
  __syncthreads();

  // ---------- attention phase ----------
  const int quad = lane >> 4, lo = lane & 15;
  const int cb = h * 32;

  bf16x8 qf[2][2], kf[2][2];
  f32x4 S[2][2];
  float ivk[2];
  if (h < 3) {
#pragma unroll
    for (int mt = 0; mt < 2; ++mt)
#pragma unroll
      for (int kt = 0; kt < 2; ++kt) {
        const int rr = kt * 4 + quad;
        const int cq = cb + mt * 16 + lo;
        const int ck = 96 + cq;
        bf16x8 q8, k8;
#pragma unroll
        for (int j = 0; j < 8; ++j) {
          q8[j] = (short)outS[(rr * 8 + j) * 296 + cq];
          k8[j] = (short)outS[(rr * 8 + j) * 296 + ck];
        }
        qf[mt][kt] = q8;
        kf[mt][kt] = k8;
      }

#pragma unroll
    for (int mt = 0; mt < 2; ++mt)
#pragma unroll
      for (int nt = 0; nt < 2; ++nt) {
        S[mt][nt] = {0.f, 0.f, 0.f, 0.f};
#pragma unroll
        for (int kt = 0; kt < 2; ++kt)
          S[mt][nt] = __builtin_amdgcn_mfma_f32_16x16x32_bf16(qf[mt][kt], kf[nt][kt], S[mt][nt], 0, 0, 0);
      }

#pragma unroll
    for (int mt = 0; mt < 2; ++mt) {
      float sq = 0.f, sk = 0.f;
#pragma unroll
      for (int kt = 0; kt < 2; ++kt)
#pragma unroll
        for (int j = 0; j < 8; ++j) {
          float a = b2f((unsigned short)qf[mt][kt][j]);
          float b = b2f((unsigned short)kf[mt][kt][j]);
          sq += a * a;
          sk += b * b;
        }
      sq += __shfl_xor(sq, 16);
      sq += __shfl_xor(sq, 32);
      sk += __shfl_xor(sk, 16);
      sk += __shfl_xor(sk, 32);
      if (quad == 0) invn[h * 32 + mt * 16 + lo] = 1.f / fmaxf(sqrtf(sq), 1e-12f);
      ivk[mt] = 1.f / fmaxf(sqrtf(sk), 1e-12f);
    }
  }
  __syncthreads();

  if (h < 3) {
    const float ts = temp[h];
#pragma unroll
    for (int mt = 0; mt < 2; ++mt)
#pragma unroll
      for (int nt = 0; nt < 2; ++nt)
#pragma unroll
        for (int r = 0; r < 4; ++r) {
          int c = mt * 16 + quad * 4 + r;
          float v = S[mt][nt][r] * invn[h * 32 + c] * ivk[nt] * ts;
          attnL[(h * 32 + c) * 40 + nt * 16 + lo] = f2b(fmaxf(v, 0.f));
        }
  }
  __syncthreads();

  f32x4 O[2][4];
  if (h < 3) {
    bf16x8 af[2];
#pragma unroll
    for (int mt = 0; mt < 2; ++mt)
      af[mt] = *(const bf16x8*)&attnL[(h * 32 + mt * 16 + lo) * 40 + quad * 8];

    const int uv = 24 + h * 4 + quad;
#pragma unroll
    for (int nt = 0; nt < 4; ++nt) {
      const int px = nt * 16 + lo;
      uint4 vraw = *(const uint4*)&outS[px * 296 + uv * 8];
      bf16x8 vf = *reinterpret_cast<bf16x8*>(&vraw);
#pragma unroll
      for (int mt = 0; mt < 2; ++mt) {
        f32x4 z = {0.f, 0.f, 0.f, 0.f};
        O[mt][nt] = __builtin_amdgcn_mfma_f32_16x16x32_bf16(af[mt], vf, z, 0, 0, 0);
      }
    }
  }
  __syncthreads();   // outS (V) dead -> Cs overlay

  unsigned short* Cs = outS;  // [64 px][104] overlay
  if (h < 3) {
#pragma unroll
    for (int mt = 0; mt < 2; ++mt)
#pragma unroll
      for (int nt = 0; nt < 4; ++nt) {
        const int px = nt * 16 + lo;
        unsigned int p0 = (unsigned int)f2b(O[mt][nt][0]) | ((unsigned int)f2b(O[mt][nt][1]) << 16);
        unsigned int p1 = (unsigned int)f2b(O[mt][nt][2]) | ((unsigned int)f2b(O[mt][nt][3]) << 16);
        *(uint2*)&Cs[px * 104 + cb + mt * 16 + quad * 4] = make_uint2(p0, p1);
      }
  }
  __syncthreads();

  // epilogue: plane-major tout [t][u][4096 px]; wave handles one plane per pass.
  for (int idx = tid; idx < 64 * 12; idx += 256) {
    int u = idx >> 6, rec = idx & 63;
    int r = rec >> 3, j = rec & 7;
    size_t local = (size_t)(wy * 8 + r) * 64 + wx * 8 + j;
    ((uint4*)tout)[((size_t)t * 12 + u) * 4096 + local] = ((const uint4*)(Cs + rec * 104))[u];
  }
}

// ---------------- k_avgproj v3: plane-major tout gather (coalesced), A-only LDS ----------------
__global__ __launch_bounds__(256, 4) void k_avgproj(const float* __restrict__ w,
                                                    const unsigned short* __restrict__ tout,
                                                    float* __restrict__ outf) {
  __shared__ __align__(16) unsigned short As[96 * 104];
  const int tid = threadIdx.x;
  const int wid = tid >> 6, lane = tid & 63;
  const int quad = lane >> 4, lo = lane & 15;
  const int px0 = blockIdx.x * 64;
  const int px = px0 + wid * 16 + lo;

  for (int l = tid; l < 96 * 24; l += 256) {
    int o = l / 24, c4 = (l - (l / 24) * 24) * 4;
    float4 v = *(const float4*)&w[o * 96 + c4];
    unsigned int p0 = (unsigned int)f2b(v.x) | ((unsigned int)f2b(v.y) << 16);
    unsigned int p1 = (unsigned int)f2b(v.z) | ((unsigned int)f2b(v.w) << 16);
    *(uint2*)&As[o * 104 + c4] = make_uint2(p0, p1);
  }

  const int y = px / W_, xx = px - y * W_;
  int loy = (y >= 64) ? (y - 14) / 50 : 0;
  int hiy = y / 50; if (hiy > 4) hiy = 4;
  int lox = (xx >= 64) ? (xx - 14) / 50 : 0;
  int hix = xx / 50; if (hix > 4) hix = 4;
  float a24[24];
#pragma unroll
  for (int i = 0; i < 24; ++i) a24[i] = 0.f;
  int cnt = 0;
  for (int ty = loy; ty <= hiy; ++ty)
    for (int tx = lox; tx <= hix; ++tx) {
      size_t local = (size_t)((y - ty * 50) << 6) + (xx - tx * 50);
      const uint4* rp = (const uint4*)tout +
                        ((size_t)(ty * 5 + tx) * 12 + quad) * 4096 + local;
#pragma unroll
      for (int ks = 0; ks < 3; ++ks) {
        uint4 v = rp[(size_t)ks * 4 * 4096];
        a24[ks * 8 + 0] += lo_f(v.x); a24[ks * 8 + 1] += hi_f(v.x);
        a24[ks * 8 + 2] += lo_f(v.y); a24[ks * 8 + 3] += hi_f(v.y);
        a24[ks * 8 + 4] += lo_f(v.z); a24[ks * 8 + 5] += hi_f(v.z);
        a24[ks * 8 + 6] += lo_f(v.w); a24[ks * 8 + 7] += hi_f(v.w);
      }
      ++cnt;
    }
  const float inv = 1.f / (float)cnt;
  bf16x8 bf[3];
#pragma unroll
  for (int ks = 0; ks < 3; ++ks) {
    union { bf16x8 v; unsigned short s[8]; } u;
#pragma unroll
    for (int i = 0; i < 8; ++i) u.s[i] = f2b(a24[ks * 8 + i] * inv);
    bf[ks] = u.v;
  }
  __syncthreads();

  f32x4 acc[6];
#pragma unroll
  for (int mt = 0; mt < 6; ++mt) acc[mt] = {0.f, 0.f, 0.f, 0.f};
#pragma unroll
  for (int ks = 0; ks < 3; ++ks) {
    const int kb = ks * 32 + quad * 8;
#pragma unroll
    for (int mt = 0; mt < 6; ++mt) {
      bf16x8 a = *(const bf16x8*)&As[(mt * 16 + lo) * 104 + kb];
      acc[mt] = __builtin_amdgcn_mfma_f32_16x16x32_bf16(a, bf[ks], acc[mt], 0, 0, 0);
    }
  }

  {
    int y2 = y + 4; if (y2 >= H_) y2 -= H_;
    int x2 = xx + 4; if (x2 >= W_) x2 -= W_;
    int tp = y2 * W_ + x2;
#pragma unroll
    for (int mt = 0; mt < 6; ++mt) {
      int row = mt * 16 + quad * 4;
#pragma unroll
      for (int r = 0; r < 4; ++r)
        outf[(size_t)(row + r) * HW_ + tp] = acc[mt][r];
    }
  }
}

extern "C" void kernel_launch(void* const* d_in, const int* in_sizes, int n_in,
                              void* d_out, int out_size, void* d_ws, size_t ws_size,
                              hipStream_t stream) {
  (void)in_sizes; (void)n_in; (void)out_size; (void)ws_size;
  const float* x = (const float*)d_in[0];
  const float* temp = (const float*)d_in[1];
  const float* qkvw = (const float*)d_in[2];
  const float* dww = (const float*)d_in[3];
  const float* projw = (const float*)d_in[4];
  float* out = (float*)d_out;

  char* ws = (char*)d_ws;
  const size_t SZQ = (size_t)288 * HW_ * 2;  // 40,144,896 B
  unsigned short* qkvb = (unsigned short*)ws;
  unsigned short* tout = (unsigned short*)(ws + SZQ);

  k_gemm<<<dim3(1089), 256, 0, stream>>>(x, qkvw, qkvb);
  k_dwattn<<<dim3(64, 25), 256, 0, stream>>>(qkvb, dww, temp, tout);
  k_avgproj<<<dim3(1089), 256, 0, stream>>>(projw, tout, out);
}